// Round 9
// baseline (114.395 us; speedup 1.0000x reference)
//
#include <hip/hip_runtime.h>
#include <cfloat>

#define NB 4096           // nodes per batch
#define FD 64             // feature dim
#define QPB 4             // queries per block (one per wave)
#define LRELU_ALPHA 0.2f
#define CCAP 96           // per-query candidate cap (E[cands] ~ 26)

// prep: Wh = x@W (8192 rows), f1 = Wh@a[:64], f2 = Wh@a[64:]
// 256 blocks x 32 rows; W staged once per block.
__global__ __launch_bounds__(256) void prep_kernel(
    const float* __restrict__ x, const float* __restrict__ W,
    const float* __restrict__ a,
    float* __restrict__ Wh, float* __restrict__ f1, float* __restrict__ f2)
{
    __shared__ float sW[FD * FD];
    const int tid = threadIdx.x;
    #pragma unroll
    for (int t = 0; t < 16; ++t) sW[tid + t * 256] = W[tid + t * 256];
    __syncthreads();
    const int lane = tid & 63, wave = tid >> 6;
    const float a1v = a[lane], a2v = a[FD + lane];
    const int rbase = blockIdx.x * 32 + wave * 8;
    #pragma unroll 2
    for (int j = 0; j < 8; ++j) {
        const int row = rbase + j;
        const float xv = x[((size_t)row << 6) + lane];
        float acc = 0.f;
        #pragma unroll
        for (int i = 0; i < FD; ++i)
            acc = fmaf(__shfl(xv, i, 64), sW[i * FD + lane], acc);
        Wh[((size_t)row << 6) + lane] = acc;
        float r1 = acc * a1v, r2 = acc * a2v;
        #pragma unroll
        for (int off = 32; off > 0; off >>= 1) {
            r1 += __shfl_down(r1, off, 64);
            r2 += __shfl_down(r2, off, 64);
        }
        if (lane == 0) { f1[row] = r1; f2[row] = r2; }
    }
}

// 4 queries/block. Pass 1: fast fma screen + per-wave bitonic of 64 disjoint-
// group minima -> provable bound T. Pass 2: append-INDEX-only branch body.
// Select: exact rn-order d2 on ~26 candidates -> u64 (d2,idx) rank =
// bit-identical jax.lax.top_k stable order; rank 0 dropped (= ref col 0).
// Phase B: gather f2, wave softmax, 20 coalesced Wh-row fmas.
__global__ __launch_bounds__(256) void gat_fused(
    const float* __restrict__ pos, const float* __restrict__ Wh,
    const float* __restrict__ f1, const float* __restrict__ f2,
    const float* __restrict__ Wp, const float* __restrict__ bp,
    const int* __restrict__ kptr, float* __restrict__ out)
{
    __shared__ union Pool {
        float tmin[QPB * 256];                         // phase A1 (4 KB)
        struct {
            unsigned long long pkbuf[QPB][CCAP];       // select (3 KB)
            int cidx[QPB][CCAP];                       // pass 2 (1.5 KB)
        } s;
    } pool;
    __shared__ float4 sq[QPB];                         // qx,qy,qz,|q|^2 (rn)
    __shared__ float sT[QPB];
    __shared__ unsigned int cnt[QPB];
    __shared__ int idx21[QPB][24];

    const int tid = threadIdx.x;
    const int lane = tid & 63, wave = tid >> 6;
    const int qbase = blockIdx.x * QPB;                // row of query 0
    const int b = qbase >> 12;                         // same batch (4096%4==0)
    const float* posb = pos + (size_t)b * NB * 3;
    const int k = *kptr;                               // 20

    if (tid < QPB) {
        const int nq = (qbase + tid) & (NB - 1);
        const float ax = posb[nq * 3 + 0], ay = posb[nq * 3 + 1], az = posb[nq * 3 + 2];
        const float sr = __fadd_rn(__fadd_rn(__fmul_rn(ax, ax), __fmul_rn(ay, ay)),
                                   __fmul_rn(az, az));
        sq[tid] = make_float4(ax, ay, az, sr);
        cnt[tid] = 0;
    }
    // safety net: in-bounds defaults (provably overwritten; avoids OOB if a
    // corner ever yields cn<k+1)
    if (lane < 24) idx21[wave][lane] = (qbase + wave) & (NB - 1);
    __syncthreads();                                   // B1

    const float4 q0 = sq[0], q1 = sq[1], q2 = sq[2], q3 = sq[3];

    // pass 1: fast screen, per-thread min per query over 16 consecutive nodes
    const float4* p4 = (const float4*)posb;
    float f0 = FLT_MAX, f1m = FLT_MAX, f2m = FLT_MAX, f3m = FLT_MAX;
    #pragma unroll
    for (int c = 0; c < 4; ++c) {
        const float4 a0 = p4[tid * 12 + c * 3 + 0];
        const float4 a1 = p4[tid * 12 + c * 3 + 1];
        const float4 a2 = p4[tid * 12 + c * 3 + 2];
        const float pxs[4] = {a0.x, a0.w, a1.z, a2.y};
        const float pys[4] = {a0.y, a1.x, a1.w, a2.z};
        const float pzs[4] = {a0.z, a1.y, a2.x, a2.w};
        #pragma unroll
        for (int j = 0; j < 4; ++j) {
            const float px = pxs[j], py = pys[j], pz = pzs[j];
            const float sm = fmaf(pz, pz, fmaf(py, py, px * px));
            float d;
            d = fmaf(-2.f, fmaf(q0.x, px, fmaf(q0.y, py, q0.z * pz)), q0.w + sm);
            f0 = fminf(f0, d);
            d = fmaf(-2.f, fmaf(q1.x, px, fmaf(q1.y, py, q1.z * pz)), q1.w + sm);
            f1m = fminf(f1m, d);
            d = fmaf(-2.f, fmaf(q2.x, px, fmaf(q2.y, py, q2.z * pz)), q2.w + sm);
            f2m = fminf(f2m, d);
            d = fmaf(-2.f, fmaf(q3.x, px, fmaf(q3.y, py, q3.z * pz)), q3.w + sm);
            f3m = fminf(f3m, d);
        }
    }
    pool.tmin[0 * 256 + tid] = f0;  pool.tmin[1 * 256 + tid] = f1m;
    pool.tmin[2 * 256 + tid] = f2m; pool.tmin[3 * 256 + tid] = f3m;
    __syncthreads();                                   // B2

    // wave w: bitonic-sort 64 disjoint-group minima of query w; sorted[k] is
    // >= global (k+1)-th smallest (k+1 distinct groups each contribute one).
    float v = fminf(fminf(pool.tmin[wave * 256 + lane],
                          pool.tmin[wave * 256 + 64 + lane]),
                    fminf(pool.tmin[wave * 256 + 128 + lane],
                          pool.tmin[wave * 256 + 192 + lane]));
    #pragma unroll
    for (int kk2 = 2; kk2 <= 64; kk2 <<= 1) {
        #pragma unroll
        for (int j = kk2 >> 1; j > 0; j >>= 1) {
            const float o = __shfl_xor(v, j, 64);
            const bool keepMin = (((lane & j) == 0) == ((lane & kk2) == 0));
            v = keepMin ? fminf(v, o) : fmaxf(v, o);
        }
    }
    // R8 bug: __shfl inside `if(lane==0)` reads an EXEC-masked-off lane ->
    // returns 0 (ds_bpermute semantics). Hoist: all lanes execute the shfl.
    const float Tq = __shfl(v, k, 64);
    if (lane == 0) sT[wave] = Tq;
    __syncthreads();                                   // B3 (tmin dead -> s.*)

    // slack >> 2x max |fast-exact| rounding gap -> candidates ⊇ exact top-(k+1)
    const float Ts0 = sT[0] + 1e-2f + 1e-3f * fabsf(sT[0]);
    const float Ts1 = sT[1] + 1e-2f + 1e-3f * fabsf(sT[1]);
    const float Ts2 = sT[2] + 1e-2f + 1e-3f * fabsf(sT[2]);
    const float Ts3 = sT[3] + 1e-2f + 1e-3f * fabsf(sT[3]);

    // pass 2: re-screen; append index only (tiny branch body)
    #pragma unroll
    for (int c = 0; c < 4; ++c) {
        const float4 a0 = p4[tid * 12 + c * 3 + 0];
        const float4 a1 = p4[tid * 12 + c * 3 + 1];
        const float4 a2 = p4[tid * 12 + c * 3 + 2];
        const float pxs[4] = {a0.x, a0.w, a1.z, a2.y};
        const float pys[4] = {a0.y, a1.x, a1.w, a2.z};
        const float pzs[4] = {a0.z, a1.y, a2.x, a2.w};
        #pragma unroll
        for (int j = 0; j < 4; ++j) {
            const float px = pxs[j], py = pys[j], pz = pzs[j];
            const float sm = fmaf(pz, pz, fmaf(py, py, px * px));
            const int m = tid * 16 + c * 4 + j;
            float d;
            d = fmaf(-2.f, fmaf(q0.x, px, fmaf(q0.y, py, q0.z * pz)), q0.w + sm);
            if (d <= Ts0) {
                const unsigned int p = atomicAdd(&cnt[0], 1u);
                if (p < CCAP) pool.s.cidx[0][p] = m;
            }
            d = fmaf(-2.f, fmaf(q1.x, px, fmaf(q1.y, py, q1.z * pz)), q1.w + sm);
            if (d <= Ts1) {
                const unsigned int p = atomicAdd(&cnt[1], 1u);
                if (p < CCAP) pool.s.cidx[1][p] = m;
            }
            d = fmaf(-2.f, fmaf(q2.x, px, fmaf(q2.y, py, q2.z * pz)), q2.w + sm);
            if (d <= Ts2) {
                const unsigned int p = atomicAdd(&cnt[2], 1u);
                if (p < CCAP) pool.s.cidx[2][p] = m;
            }
            d = fmaf(-2.f, fmaf(q3.x, px, fmaf(q3.y, py, q3.z * pz)), q3.w + sm);
            if (d <= Ts3) {
                const unsigned int p = atomicAdd(&cnt[3], 1u);
                if (p < CCAP) pool.s.cidx[3][p] = m;
            }
        }
    }
    __syncthreads();                                   // B4 — last barrier

    // select (wave w <- query w): exact rn-order d2 on candidates, u64 rank
    const float4 qq = sq[wave];
    const int cn0 = (int)cnt[wave];
    const int cn = cn0 < CCAP ? cn0 : CCAP;
    for (int e = lane; e < cn; e += 64) {
        const int m = pool.s.cidx[wave][e];
        const float px = posb[m * 3 + 0];
        const float py = posb[m * 3 + 1];
        const float pz = posb[m * 3 + 2];
        const float sqm = __fadd_rn(__fadd_rn(__fmul_rn(px, px), __fmul_rn(py, py)),
                                    __fmul_rn(pz, pz));
        const float dot = __fadd_rn(__fadd_rn(__fmul_rn(qq.x, px), __fmul_rn(qq.y, py)),
                                    __fmul_rn(qq.z, pz));
        const float d2 = __fsub_rn(__fadd_rn(qq.w, sqm), __fmul_rn(2.0f, dot));
        const unsigned int u = __float_as_uint(d2);
        const unsigned int kk = u ^ ((unsigned int)((int)u >> 31) | 0x80000000u);
        pool.s.pkbuf[wave][e] = ((unsigned long long)kk << 12) | (unsigned int)m;
    }
    for (int e = lane; e < cn; e += 64) {
        const unsigned long long xv = pool.s.pkbuf[wave][e];
        int r = 0;
        for (int j = 0; j < cn; ++j) r += (pool.s.pkbuf[wave][j] < xv);
        if (r <= k) idx21[wave][r] = (int)(xv & 0xFFFu);
    }
    // wave-private LDS RAW: in-order per wave + compiler lgkmcnt, no barrier

    // phase B (wave-private): scores, softmax, Wh-row gather
    const int row = qbase + wave;
    const bool valid = (lane >= 1 && lane <= k);
    const int nbr = valid ? idx21[wave][lane] : 0;
    const float f1v = f1[row];
    float e = -FLT_MAX;
    if (valid) {
        e = f1v + f2[(b << 12) + nbr];
        e = e > 0.f ? e : LRELU_ALPHA * e;
    }
    float mx = e;
    #pragma unroll
    for (int off = 32; off > 0; off >>= 1) mx = fmaxf(mx, __shfl_xor(mx, off, 64));
    const float ex = valid ? __expf(e - mx) : 0.f;
    float Z = ex;
    #pragma unroll
    for (int off = 32; off > 0; off >>= 1) Z += __shfl_xor(Z, off, 64);
    const float attn = ex / Z;                         // lane t holds attn_t

    const float* whb = Wh + (((size_t)b << 12) << 6);
    float h = 0.f;
    #pragma unroll 4
    for (int t = 1; t <= k; ++t) {
        const int nb_ = __shfl(nbr, t, 64);
        const float s = __shfl(attn, t, 64);
        h = fmaf(s, whb[((size_t)nb_ << 6) + lane], h);
    }

    const float pv = fmaf(qq.x, Wp[0 * FD + lane],
                     fmaf(qq.y, Wp[1 * FD + lane],
                     fmaf(qq.z, Wp[2 * FD + lane], bp[lane])));
    h += pv > 0.f ? pv : 0.f;
    out[((size_t)row << 6) + lane] = h > 0.f ? h : expm1f(h);
}

extern "C" void kernel_launch(void* const* d_in, const int* in_sizes, int n_in,
                              void* d_out, int out_size, void* d_ws, size_t ws_size,
                              hipStream_t stream) {
    const float* x   = (const float*)d_in[0];
    const float* pos = (const float*)d_in[1];
    const float* W   = (const float*)d_in[2];
    const float* a   = (const float*)d_in[3];
    const float* Wp  = (const float*)d_in[4];
    const float* bp  = (const float*)d_in[5];
    const int*   kp  = (const int*)d_in[6];

    float* ws = (float*)d_ws;
    float* Wh = ws;                 // 8192*64
    float* f1 = Wh + 524288;        // 8192
    float* f2 = f1 + 8192;          // 8192
    float* out = (float*)d_out;

    prep_kernel<<<256, 256, 0, stream>>>(x, W, a, Wh, f1, f2);
    gat_fused<<<(NB * 2) / QPB, 256, 0, stream>>>(pos, Wh, f1, f2, Wp, bp, kp, out);
}

// Round 10
// 112.359 us; speedup vs baseline: 1.0181x; 1.0181x over previous
//
#include <hip/hip_runtime.h>
#include <cfloat>

#define NB 4096           // nodes per batch
#define FD 64             // feature dim
#define QPB 4             // queries per block (one per wave)
#define LRELU_ALPHA 0.2f
#define CCAP 96           // per-query candidate cap (E[cands] ~ 26)

// prep: Wh = x@W (8192 rows), f1 = Wh@a[:64], f2 = Wh@a[64:]
// 512 blocks x 16 rows; 4 rows/wave with 2-row ILP.
__global__ __launch_bounds__(256) void prep_kernel(
    const float* __restrict__ x, const float* __restrict__ W,
    const float* __restrict__ a,
    float* __restrict__ Wh, float* __restrict__ f1, float* __restrict__ f2)
{
    __shared__ float sW[FD * FD];
    const int tid = threadIdx.x;
    #pragma unroll
    for (int t = 0; t < 16; ++t) sW[tid + t * 256] = W[tid + t * 256];
    __syncthreads();
    const int lane = tid & 63, wave = tid >> 6;
    const float a1v = a[lane], a2v = a[FD + lane];
    const int rbase = blockIdx.x * 16 + wave * 4;
    #pragma unroll
    for (int j = 0; j < 4; j += 2) {                 // 2 rows in flight (ILP)
        const int r0 = rbase + j, r1 = rbase + j + 1;
        const float xv0 = x[((size_t)r0 << 6) + lane];
        const float xv1 = x[((size_t)r1 << 6) + lane];
        float acc0 = 0.f, acc1 = 0.f;
        #pragma unroll
        for (int i = 0; i < FD; ++i) {
            const float wv = sW[i * FD + lane];
            acc0 = fmaf(__shfl(xv0, i, 64), wv, acc0);
            acc1 = fmaf(__shfl(xv1, i, 64), wv, acc1);
        }
        Wh[((size_t)r0 << 6) + lane] = acc0;
        Wh[((size_t)r1 << 6) + lane] = acc1;
        float s10 = acc0 * a1v, s20 = acc0 * a2v;
        float s11 = acc1 * a1v, s21 = acc1 * a2v;
        #pragma unroll
        for (int off = 32; off > 0; off >>= 1) {
            s10 += __shfl_down(s10, off, 64);
            s20 += __shfl_down(s20, off, 64);
            s11 += __shfl_down(s11, off, 64);
            s21 += __shfl_down(s21, off, 64);
        }
        if (lane == 0) { f1[r0] = s10; f2[r0] = s20; f1[r1] = s11; f2[r1] = s21; }
    }
}

// 4 queries/block. Node stream uses stride-256 interleave (m = t*256+tid):
// lanes 12 B apart -> the 3 scalar dword loads/iter touch the same ~6 cache
// lines (true coalescing). [R5-R9 used tid*192-strided float4 = 64 lines per
// wave-load: L1-service-bound, the hidden floor of those rounds.]
// Pass 1: fast fma screen + per-wave bitonic of 64 disjoint-group minima ->
// provable bound T. Pass 2: append-index-only. Select: exact rn-order d2 on
// ~26 candidates -> u64 (d2,idx) rank = bit-identical jax.lax.top_k stable
// order; rank 0 dropped (= ref col 0). Phase B: wave-private softmax + 20
// coalesced Wh-row fmas.
__global__ __launch_bounds__(256) void gat_fused(
    const float* __restrict__ pos, const float* __restrict__ Wh,
    const float* __restrict__ f1, const float* __restrict__ f2,
    const float* __restrict__ Wp, const float* __restrict__ bp,
    const int* __restrict__ kptr, float* __restrict__ out)
{
    __shared__ union Pool {
        float tmin[QPB * 256];                         // phase A1 (4 KB)
        struct {
            unsigned long long pkbuf[QPB][CCAP];       // select (3 KB)
            int cidx[QPB][CCAP];                       // pass 2 (1.5 KB)
        } s;
    } pool;
    __shared__ float4 sq[QPB];                         // qx,qy,qz,|q|^2 (rn)
    __shared__ float sT[QPB];
    __shared__ unsigned int cnt[QPB];
    __shared__ int idx21[QPB][24];

    const int tid = threadIdx.x;
    const int lane = tid & 63, wave = tid >> 6;
    const int qbase = blockIdx.x * QPB;                // row of query 0
    const int b = qbase >> 12;                         // same batch (4096%4==0)
    const float* posb = pos + (size_t)b * NB * 3;
    const int k = *kptr;                               // 20

    if (tid < QPB) {
        const int nq = (qbase + tid) & (NB - 1);
        const float ax = posb[nq * 3 + 0], ay = posb[nq * 3 + 1], az = posb[nq * 3 + 2];
        const float sr = __fadd_rn(__fadd_rn(__fmul_rn(ax, ax), __fmul_rn(ay, ay)),
                                   __fmul_rn(az, az));
        sq[tid] = make_float4(ax, ay, az, sr);
        cnt[tid] = 0;
    }
    // safety net: in-bounds defaults (provably overwritten; avoids OOB if a
    // corner ever yields cn<k+1)
    if (lane < 24) idx21[wave][lane] = (qbase + wave) & (NB - 1);
    __syncthreads();                                   // B1

    const float4 q0 = sq[0], q1 = sq[1], q2 = sq[2], q3 = sq[3];

    // pass 1: fast screen, per-thread min per query, coalesced node stream
    float f0 = FLT_MAX, f1m = FLT_MAX, f2m = FLT_MAX, f3m = FLT_MAX;
    #pragma unroll
    for (int t = 0; t < 16; ++t) {
        const int m = t * 256 + tid;
        const float px = posb[m * 3 + 0];
        const float py = posb[m * 3 + 1];
        const float pz = posb[m * 3 + 2];
        const float sm = fmaf(pz, pz, fmaf(py, py, px * px));
        float d;
        d = fmaf(-2.f, fmaf(q0.x, px, fmaf(q0.y, py, q0.z * pz)), q0.w + sm);
        f0 = fminf(f0, d);
        d = fmaf(-2.f, fmaf(q1.x, px, fmaf(q1.y, py, q1.z * pz)), q1.w + sm);
        f1m = fminf(f1m, d);
        d = fmaf(-2.f, fmaf(q2.x, px, fmaf(q2.y, py, q2.z * pz)), q2.w + sm);
        f2m = fminf(f2m, d);
        d = fmaf(-2.f, fmaf(q3.x, px, fmaf(q3.y, py, q3.z * pz)), q3.w + sm);
        f3m = fminf(f3m, d);
    }
    pool.tmin[0 * 256 + tid] = f0;  pool.tmin[1 * 256 + tid] = f1m;
    pool.tmin[2 * 256 + tid] = f2m; pool.tmin[3 * 256 + tid] = f3m;
    __syncthreads();                                   // B2

    // wave w: bitonic-sort 64 disjoint-group minima of query w; sorted[k] is
    // >= global (k+1)-th smallest (k+1 distinct groups each contribute one).
    float v = fminf(fminf(pool.tmin[wave * 256 + lane],
                          pool.tmin[wave * 256 + 64 + lane]),
                    fminf(pool.tmin[wave * 256 + 128 + lane],
                          pool.tmin[wave * 256 + 192 + lane]));
    #pragma unroll
    for (int kk2 = 2; kk2 <= 64; kk2 <<= 1) {
        #pragma unroll
        for (int j = kk2 >> 1; j > 0; j >>= 1) {
            const float o = __shfl_xor(v, j, 64);
            const bool keepMin = (((lane & j) == 0) == ((lane & kk2) == 0));
            v = keepMin ? fminf(v, o) : fmaxf(v, o);
        }
    }
    const float Tq = __shfl(v, k, 64);                 // all lanes execute (R8 lesson)
    if (lane == 0) sT[wave] = Tq;
    __syncthreads();                                   // B3 (tmin dead -> s.*)

    // slack >> 2x max |fast-exact| rounding gap -> candidates ⊇ exact top-(k+1)
    const float Ts0 = sT[0] + 1e-2f + 1e-3f * fabsf(sT[0]);
    const float Ts1 = sT[1] + 1e-2f + 1e-3f * fabsf(sT[1]);
    const float Ts2 = sT[2] + 1e-2f + 1e-3f * fabsf(sT[2]);
    const float Ts3 = sT[3] + 1e-2f + 1e-3f * fabsf(sT[3]);

    // pass 2: re-screen (same coalesced stream); append index only
    #pragma unroll
    for (int t = 0; t < 16; ++t) {
        const int m = t * 256 + tid;
        const float px = posb[m * 3 + 0];
        const float py = posb[m * 3 + 1];
        const float pz = posb[m * 3 + 2];
        const float sm = fmaf(pz, pz, fmaf(py, py, px * px));
        float d;
        d = fmaf(-2.f, fmaf(q0.x, px, fmaf(q0.y, py, q0.z * pz)), q0.w + sm);
        if (d <= Ts0) {
            const unsigned int p = atomicAdd(&cnt[0], 1u);
            if (p < CCAP) pool.s.cidx[0][p] = m;
        }
        d = fmaf(-2.f, fmaf(q1.x, px, fmaf(q1.y, py, q1.z * pz)), q1.w + sm);
        if (d <= Ts1) {
            const unsigned int p = atomicAdd(&cnt[1], 1u);
            if (p < CCAP) pool.s.cidx[1][p] = m;
        }
        d = fmaf(-2.f, fmaf(q2.x, px, fmaf(q2.y, py, q2.z * pz)), q2.w + sm);
        if (d <= Ts2) {
            const unsigned int p = atomicAdd(&cnt[2], 1u);
            if (p < CCAP) pool.s.cidx[2][p] = m;
        }
        d = fmaf(-2.f, fmaf(q3.x, px, fmaf(q3.y, py, q3.z * pz)), q3.w + sm);
        if (d <= Ts3) {
            const unsigned int p = atomicAdd(&cnt[3], 1u);
            if (p < CCAP) pool.s.cidx[3][p] = m;
        }
    }
    __syncthreads();                                   // B4 — last barrier

    // select (wave w <- query w): exact rn-order d2 on candidates, u64 rank
    const float4 qq = sq[wave];
    const int cn0 = (int)cnt[wave];
    const int cn = cn0 < CCAP ? cn0 : CCAP;
    for (int e = lane; e < cn; e += 64) {
        const int m = pool.s.cidx[wave][e];
        const float px = posb[m * 3 + 0];
        const float py = posb[m * 3 + 1];
        const float pz = posb[m * 3 + 2];
        const float sqm = __fadd_rn(__fadd_rn(__fmul_rn(px, px), __fmul_rn(py, py)),
                                    __fmul_rn(pz, pz));
        const float dot = __fadd_rn(__fadd_rn(__fmul_rn(qq.x, px), __fmul_rn(qq.y, py)),
                                    __fmul_rn(qq.z, pz));
        const float d2 = __fsub_rn(__fadd_rn(qq.w, sqm), __fmul_rn(2.0f, dot));
        const unsigned int u = __float_as_uint(d2);
        const unsigned int kk = u ^ ((unsigned int)((int)u >> 31) | 0x80000000u);
        pool.s.pkbuf[wave][e] = ((unsigned long long)kk << 12) | (unsigned int)m;
    }
    for (int e = lane; e < cn; e += 64) {
        const unsigned long long xv = pool.s.pkbuf[wave][e];
        int r = 0;
        for (int j = 0; j < cn; ++j) r += (pool.s.pkbuf[wave][j] < xv);
        if (r <= k) idx21[wave][r] = (int)(xv & 0xFFFu);
    }
    // wave-private LDS RAW: in-order per wave + compiler lgkmcnt, no barrier

    // phase B (wave-private): scores, softmax, Wh-row gather
    const int row = qbase + wave;
    const bool valid = (lane >= 1 && lane <= k);
    const int nbr = valid ? idx21[wave][lane] : 0;
    const float f1v = f1[row];
    float e = -FLT_MAX;
    if (valid) {
        e = f1v + f2[(b << 12) + nbr];
        e = e > 0.f ? e : LRELU_ALPHA * e;
    }
    float mx = e;
    #pragma unroll
    for (int off = 32; off > 0; off >>= 1) mx = fmaxf(mx, __shfl_xor(mx, off, 64));
    const float ex = valid ? __expf(e - mx) : 0.f;
    float Z = ex;
    #pragma unroll
    for (int off = 32; off > 0; off >>= 1) Z += __shfl_xor(Z, off, 64);
    const float attn = ex / Z;                         // lane t holds attn_t

    const float* whb = Wh + (((size_t)b << 12) << 6);
    float h = 0.f;
    #pragma unroll 4
    for (int t = 1; t <= k; ++t) {
        const int nb_ = __shfl(nbr, t, 64);
        const float s = __shfl(attn, t, 64);
        h = fmaf(s, whb[((size_t)nb_ << 6) + lane], h);
    }

    const float pv = fmaf(qq.x, Wp[0 * FD + lane],
                     fmaf(qq.y, Wp[1 * FD + lane],
                     fmaf(qq.z, Wp[2 * FD + lane], bp[lane])));
    h += pv > 0.f ? pv : 0.f;
    out[((size_t)row << 6) + lane] = h > 0.f ? h : expm1f(h);
}

extern "C" void kernel_launch(void* const* d_in, const int* in_sizes, int n_in,
                              void* d_out, int out_size, void* d_ws, size_t ws_size,
                              hipStream_t stream) {
    const float* x   = (const float*)d_in[0];
    const float* pos = (const float*)d_in[1];
    const float* W   = (const float*)d_in[2];
    const float* a   = (const float*)d_in[3];
    const float* Wp  = (const float*)d_in[4];
    const float* bp  = (const float*)d_in[5];
    const int*   kp  = (const int*)d_in[6];

    float* ws = (float*)d_ws;
    float* Wh = ws;                 // 8192*64
    float* f1 = Wh + 524288;        // 8192
    float* f2 = f1 + 8192;          // 8192
    float* out = (float*)d_out;

    prep_kernel<<<512, 256, 0, stream>>>(x, W, a, Wh, f1, f2);
    gat_fused<<<(NB * 2) / QPB, 256, 0, stream>>>(pos, Wh, f1, f2, Wp, bp, kp, out);
}

// Round 11
// 100.919 us; speedup vs baseline: 1.1335x; 1.1134x over previous
//
#include <hip/hip_runtime.h>
#include <cfloat>

#define NB 4096           // nodes per batch
#define FD 64             // feature dim
#define QPB 4             // queries per block (one per wave)
#define LRELU_ALPHA 0.2f
#define CCAP 96           // per-query candidate cap (E[cands] ~ 26)

// prep: Wh = x@W (8192 rows), f1 = Wh@a[:64], f2 = Wh@a[64:]
__global__ __launch_bounds__(256) void prep_kernel(
    const float* __restrict__ x, const float* __restrict__ W,
    const float* __restrict__ a,
    float* __restrict__ Wh, float* __restrict__ f1, float* __restrict__ f2)
{
    __shared__ float sW[FD * FD];
    const int tid = threadIdx.x;
    #pragma unroll
    for (int t = 0; t < 16; ++t) sW[tid + t * 256] = W[tid + t * 256];
    __syncthreads();
    const int lane = tid & 63, wave = tid >> 6;
    const float a1v = a[lane], a2v = a[FD + lane];
    const int rbase = blockIdx.x * 16 + wave * 4;
    #pragma unroll
    for (int j = 0; j < 4; j += 2) {                 // 2 rows in flight (ILP)
        const int r0 = rbase + j, r1 = rbase + j + 1;
        const float xv0 = x[((size_t)r0 << 6) + lane];
        const float xv1 = x[((size_t)r1 << 6) + lane];
        float acc0 = 0.f, acc1 = 0.f;
        #pragma unroll
        for (int i = 0; i < FD; ++i) {
            const float wv = sW[i * FD + lane];
            acc0 = fmaf(__shfl(xv0, i, 64), wv, acc0);
            acc1 = fmaf(__shfl(xv1, i, 64), wv, acc1);
        }
        Wh[((size_t)r0 << 6) + lane] = acc0;
        Wh[((size_t)r1 << 6) + lane] = acc1;
        float s10 = acc0 * a1v, s20 = acc0 * a2v;
        float s11 = acc1 * a1v, s21 = acc1 * a2v;
        #pragma unroll
        for (int off = 32; off > 0; off >>= 1) {
            s10 += __shfl_down(s10, off, 64);
            s20 += __shfl_down(s20, off, 64);
            s11 += __shfl_down(s11, off, 64);
            s21 += __shfl_down(s21, off, 64);
        }
        if (lane == 0) { f1[r0] = s10; f2[r0] = s20; f1[r1] = s11; f2[r1] = s21; }
    }
}

// 4 queries/block. Screen metric e = 0.5|p|^2 - q.p (per-query order == d2
// order; 4 VALU/pair). Pass 1: per-thread e-min + per-wave bitonic of 64
// disjoint-group minima -> provable bound T (sorted[k] >= global (k+1)-th
// smallest e). Pass 2: append-index-only with slack >> fp32 fast-vs-rn gap
// -> candidates ⊇ exact top-(k+1). Select: exact rn-op-order d2 on ~26
// candidates -> u64 (d2,idx) rank = bit-identical jax.lax.top_k stable
// order; rank 0 dropped (= ref col 0). Phase B: wave-private softmax + 20
// coalesced Wh-row fmas. launch_bounds(256,8) + unroll-4 keep VGPR < 64
// (R10 lesson: vgpr=64 halves waves/SIMD -> occupancy 38%).
__global__ __launch_bounds__(256, 8) void gat_fused(
    const float* __restrict__ pos, const float* __restrict__ Wh,
    const float* __restrict__ f1, const float* __restrict__ f2,
    const float* __restrict__ Wp, const float* __restrict__ bp,
    const int* __restrict__ kptr, float* __restrict__ out)
{
    __shared__ union Pool {
        float tmin[QPB * 256];                         // phase A1 (4 KB)
        struct {
            unsigned long long pkbuf[QPB][CCAP];       // select (3 KB)
            int cidx[QPB][CCAP];                       // pass 2 (1.5 KB)
        } s;
    } pool;
    __shared__ float4 sq[QPB];                         // qx,qy,qz,|q|^2 (rn)
    __shared__ float sT[QPB];
    __shared__ unsigned int cnt[QPB];
    __shared__ int idx21[QPB][24];

    const int tid = threadIdx.x;
    const int lane = tid & 63, wave = tid >> 6;
    const int qbase = blockIdx.x * QPB;                // row of query 0
    const int b = qbase >> 12;                         // same batch (4096%4==0)
    const float* posb = pos + (size_t)b * NB * 3;
    const int k = *kptr;                               // 20

    if (tid < QPB) {
        const int nq = (qbase + tid) & (NB - 1);
        const float ax = posb[nq * 3 + 0], ay = posb[nq * 3 + 1], az = posb[nq * 3 + 2];
        const float sr = __fadd_rn(__fadd_rn(__fmul_rn(ax, ax), __fmul_rn(ay, ay)),
                                   __fmul_rn(az, az));
        sq[tid] = make_float4(ax, ay, az, sr);
        cnt[tid] = 0;
    }
    // safety net: in-bounds defaults (provably overwritten; avoids OOB if a
    // corner ever yields cn<k+1)
    if (lane < 24) idx21[wave][lane] = (qbase + wave) & (NB - 1);
    __syncthreads();                                   // B1

    const float4 q0 = sq[0], q1 = sq[1], q2 = sq[2], q3 = sq[3];

    // pass 1: fast screen (e-metric), coalesced interleaved node stream
    float f0 = FLT_MAX, f1m = FLT_MAX, f2m = FLT_MAX, f3m = FLT_MAX;
    #pragma unroll 4
    for (int t = 0; t < 16; ++t) {
        const int m = t * 256 + tid;
        const float px = posb[m * 3 + 0];
        const float py = posb[m * 3 + 1];
        const float pz = posb[m * 3 + 2];
        const float sm = fmaf(pz, pz, fmaf(py, py, px * px));
        float d;
        d = fmaf(0.5f, sm, -fmaf(q0.x, px, fmaf(q0.y, py, q0.z * pz)));
        f0 = fminf(f0, d);
        d = fmaf(0.5f, sm, -fmaf(q1.x, px, fmaf(q1.y, py, q1.z * pz)));
        f1m = fminf(f1m, d);
        d = fmaf(0.5f, sm, -fmaf(q2.x, px, fmaf(q2.y, py, q2.z * pz)));
        f2m = fminf(f2m, d);
        d = fmaf(0.5f, sm, -fmaf(q3.x, px, fmaf(q3.y, py, q3.z * pz)));
        f3m = fminf(f3m, d);
    }
    pool.tmin[0 * 256 + tid] = f0;  pool.tmin[1 * 256 + tid] = f1m;
    pool.tmin[2 * 256 + tid] = f2m; pool.tmin[3 * 256 + tid] = f3m;
    __syncthreads();                                   // B2

    // wave w: bitonic-sort 64 disjoint-group e-minima of query w; sorted[k]
    // >= global (k+1)-th smallest e (k+1 distinct groups contribute one each).
    float v = fminf(fminf(pool.tmin[wave * 256 + lane],
                          pool.tmin[wave * 256 + 64 + lane]),
                    fminf(pool.tmin[wave * 256 + 128 + lane],
                          pool.tmin[wave * 256 + 192 + lane]));
    #pragma unroll
    for (int kk2 = 2; kk2 <= 64; kk2 <<= 1) {
        #pragma unroll
        for (int j = kk2 >> 1; j > 0; j >>= 1) {
            const float o = __shfl_xor(v, j, 64);
            const bool keepMin = (((lane & j) == 0) == ((lane & kk2) == 0));
            v = keepMin ? fminf(v, o) : fmaxf(v, o);
        }
    }
    const float Tq = __shfl(v, k, 64);                 // all lanes execute (R8 lesson)
    if (lane == 0) sT[wave] = Tq;
    __syncthreads();                                   // B3 (tmin dead -> s.*)

    // slack (e-space): 1e-2 + 1e-3|T| >> fp32 fast-vs-rn gap (~1e-5) ->
    // candidate set provably ⊇ exact top-(k+1)
    const float Ts0 = sT[0] + 1e-2f + 1e-3f * fabsf(sT[0]);
    const float Ts1 = sT[1] + 1e-2f + 1e-3f * fabsf(sT[1]);
    const float Ts2 = sT[2] + 1e-2f + 1e-3f * fabsf(sT[2]);
    const float Ts3 = sT[3] + 1e-2f + 1e-3f * fabsf(sT[3]);

    // pass 2: re-screen (same stream); append index only
    #pragma unroll 4
    for (int t = 0; t < 16; ++t) {
        const int m = t * 256 + tid;
        const float px = posb[m * 3 + 0];
        const float py = posb[m * 3 + 1];
        const float pz = posb[m * 3 + 2];
        const float sm = fmaf(pz, pz, fmaf(py, py, px * px));
        float d;
        d = fmaf(0.5f, sm, -fmaf(q0.x, px, fmaf(q0.y, py, q0.z * pz)));
        if (d <= Ts0) {
            const unsigned int p = atomicAdd(&cnt[0], 1u);
            if (p < CCAP) pool.s.cidx[0][p] = m;
        }
        d = fmaf(0.5f, sm, -fmaf(q1.x, px, fmaf(q1.y, py, q1.z * pz)));
        if (d <= Ts1) {
            const unsigned int p = atomicAdd(&cnt[1], 1u);
            if (p < CCAP) pool.s.cidx[1][p] = m;
        }
        d = fmaf(0.5f, sm, -fmaf(q2.x, px, fmaf(q2.y, py, q2.z * pz)));
        if (d <= Ts2) {
            const unsigned int p = atomicAdd(&cnt[2], 1u);
            if (p < CCAP) pool.s.cidx[2][p] = m;
        }
        d = fmaf(0.5f, sm, -fmaf(q3.x, px, fmaf(q3.y, py, q3.z * pz)));
        if (d <= Ts3) {
            const unsigned int p = atomicAdd(&cnt[3], 1u);
            if (p < CCAP) pool.s.cidx[3][p] = m;
        }
    }
    __syncthreads();                                   // B4 — last barrier

    // select (wave w <- query w): exact rn-op-order d2 on candidates, u64 rank
    const float4 qq = sq[wave];
    const int cn0 = (int)cnt[wave];
    const int cn = cn0 < CCAP ? cn0 : CCAP;
    for (int e = lane; e < cn; e += 64) {
        const int m = pool.s.cidx[wave][e];
        const float px = posb[m * 3 + 0];
        const float py = posb[m * 3 + 1];
        const float pz = posb[m * 3 + 2];
        const float sqm = __fadd_rn(__fadd_rn(__fmul_rn(px, px), __fmul_rn(py, py)),
                                    __fmul_rn(pz, pz));
        const float dot = __fadd_rn(__fadd_rn(__fmul_rn(qq.x, px), __fmul_rn(qq.y, py)),
                                    __fmul_rn(qq.z, pz));
        const float d2 = __fsub_rn(__fadd_rn(qq.w, sqm), __fmul_rn(2.0f, dot));
        const unsigned int u = __float_as_uint(d2);
        const unsigned int kk = u ^ ((unsigned int)((int)u >> 31) | 0x80000000u);
        pool.s.pkbuf[wave][e] = ((unsigned long long)kk << 12) | (unsigned int)m;
    }
    for (int e = lane; e < cn; e += 64) {
        const unsigned long long xv = pool.s.pkbuf[wave][e];
        int r = 0;
        for (int j = 0; j < cn; ++j) r += (pool.s.pkbuf[wave][j] < xv);
        if (r <= k) idx21[wave][r] = (int)(xv & 0xFFFu);
    }
    // wave-private LDS RAW: in-order per wave + compiler lgkmcnt, no barrier

    // phase B (wave-private): scores, softmax, Wh-row gather
    const int row = qbase + wave;
    const bool valid = (lane >= 1 && lane <= k);
    const int nbr = valid ? idx21[wave][lane] : 0;
    const float f1v = f1[row];
    float e = -FLT_MAX;
    if (valid) {
        e = f1v + f2[(b << 12) + nbr];
        e = e > 0.f ? e : LRELU_ALPHA * e;
    }
    float mx = e;
    #pragma unroll
    for (int off = 32; off > 0; off >>= 1) mx = fmaxf(mx, __shfl_xor(mx, off, 64));
    const float ex = valid ? __expf(e - mx) : 0.f;
    float Z = ex;
    #pragma unroll
    for (int off = 32; off > 0; off >>= 1) Z += __shfl_xor(Z, off, 64);
    const float attn = ex / Z;                         // lane t holds attn_t

    const float* whb = Wh + (((size_t)b << 12) << 6);
    float h = 0.f;
    #pragma unroll 4
    for (int t = 1; t <= k; ++t) {
        const int nb_ = __shfl(nbr, t, 64);
        const float s = __shfl(attn, t, 64);
        h = fmaf(s, whb[((size_t)nb_ << 6) + lane], h);
    }

    const float pv = fmaf(qq.x, Wp[0 * FD + lane],
                     fmaf(qq.y, Wp[1 * FD + lane],
                     fmaf(qq.z, Wp[2 * FD + lane], bp[lane])));
    h += pv > 0.f ? pv : 0.f;
    out[((size_t)row << 6) + lane] = h > 0.f ? h : expm1f(h);
}

extern "C" void kernel_launch(void* const* d_in, const int* in_sizes, int n_in,
                              void* d_out, int out_size, void* d_ws, size_t ws_size,
                              hipStream_t stream) {
    const float* x   = (const float*)d_in[0];
    const float* pos = (const float*)d_in[1];
    const float* W   = (const float*)d_in[2];
    const float* a   = (const float*)d_in[3];
    const float* Wp  = (const float*)d_in[4];
    const float* bp  = (const float*)d_in[5];
    const int*   kp  = (const int*)d_in[6];

    float* ws = (float*)d_ws;
    float* Wh = ws;                 // 8192*64
    float* f1 = Wh + 524288;        // 8192
    float* f2 = f1 + 8192;          // 8192
    float* out = (float*)d_out;

    prep_kernel<<<512, 256, 0, stream>>>(x, W, a, Wh, f1, f2);
    gat_fused<<<(NB * 2) / QPB, 256, 0, stream>>>(pos, Wh, f1, f2, Wp, bp, kp, out);
}